// Round 15
// baseline (274.227 us; speedup 1.0000x reference)
//
#include <hip/hip_runtime.h>

#define B_ROWS 14336
#define D_DIM  512
#define C_CLS  7
#define M_CLS  2048

typedef __attribute__((ext_vector_type(4))) float f32x4;

// fp8 scale: fea*64 -> sigma~3.2 in e4m3 range; Gram scaled by 4096
#define FP8_SCALE 64.0f
#define INV_2S2   (2.0f / 4096.0f)

typedef const __attribute__((address_space(1))) char gchar_t;
typedef __attribute__((address_space(3))) char lchar_t;

__device__ __forceinline__ void gload16(const char* g, char* l) {
  // async global->LDS DMA, 16B/lane, dest = wave-uniform base + lane*16
  __builtin_amdgcn_global_load_lds((gchar_t*)g, (lchar_t*)l, 16, 0, 0);
}

// K0: fea->fp8 packed in fragment-order image + row norms + logits + zero zb
// (zb also holds the fusion counters at words 60/61).
__global__ __launch_bounds__(256) void k_prep(const float* __restrict__ fea,
                                              const float* __restrict__ W,
                                              char* __restrict__ f8p,
                                              float* __restrict__ an,
                                              float* __restrict__ logits,
                                              float* __restrict__ zb) {  // 64 floats
  int t = threadIdx.x, wave = t >> 6, lane = t & 63;
  if (blockIdx.x == 0 && t < 64) zb[t] = 0.f;
  __shared__ char lrow[16 * 528];  // 16 rows x 512B fp8 (+16 pad)

  int r0 = blockIdx.x * 16;
#pragma unroll
  for (int k = 0; k < 4; ++k) {
    int rl = wave * 4 + k;
    int row = r0 + rl;
    const float4* fr4 = (const float4*)(fea + (size_t)row * D_DIM);
    float4 v0 = fr4[lane * 2], v1 = fr4[lane * 2 + 1];

    float p[8];
#pragma unroll
    for (int c = 0; c < 7; ++c) {
      const float4* w4 = (const float4*)(W + c * D_DIM);
      float4 q0 = w4[lane * 2], q1 = w4[lane * 2 + 1];
      p[c] = v0.x * q0.x + v0.y * q0.y + v0.z * q0.z + v0.w * q0.w +
             v1.x * q1.x + v1.y * q1.y + v1.z * q1.z + v1.w * q1.w;
    }
    p[7] = v0.x * v0.x + v0.y * v0.y + v0.z * v0.z + v0.w * v0.w +
           v1.x * v1.x + v1.y * v1.y + v1.z * v1.z + v1.w * v1.w;

#pragma unroll
    for (int c = 0; c < 8; ++c) {
      p[c] += __shfl_xor(p[c], 1);
      p[c] += __shfl_xor(p[c], 2);
      p[c] += __shfl_xor(p[c], 4);
    }
    int v = lane & 7;
    float y = p[0];
    y = (v == 1) ? p[1] : y;
    y = (v == 2) ? p[2] : y;
    y = (v == 3) ? p[3] : y;
    y = (v == 4) ? p[4] : y;
    y = (v == 5) ? p[5] : y;
    y = (v == 6) ? p[6] : y;
    y = (v == 7) ? p[7] : y;
    y += __shfl_xor(y, 8);
    y += __shfl_xor(y, 16);
    y += __shfl_xor(y, 32);
    if (lane < 7) logits[row * 7 + lane] = y;
    else if (lane == 7) an[row] = y;

    int w0 = __builtin_amdgcn_cvt_pk_fp8_f32(v0.x * FP8_SCALE, v0.y * FP8_SCALE, 0, 0);
    w0     = __builtin_amdgcn_cvt_pk_fp8_f32(v0.z * FP8_SCALE, v0.w * FP8_SCALE, w0, 1);
    int w1 = __builtin_amdgcn_cvt_pk_fp8_f32(v1.x * FP8_SCALE, v1.y * FP8_SCALE, 0, 0);
    w1     = __builtin_amdgcn_cvt_pk_fp8_f32(v1.z * FP8_SCALE, v1.w * FP8_SCALE, w1, 1);
    *(int2*)&lrow[rl * 528 + lane * 8] = make_int2(w0, w1);
  }
  __syncthreads();
  int4* outp = (int4*)f8p + (size_t)blockIdx.x * 512;
#pragma unroll
  for (int pi = 0; pi < 2; ++pi) {
    int idx = pi * 256 + t;          // [0,512) = (kp, l)
    int kp = idx >> 6, l = idx & 63;
    int sr = l & 15, qk = l >> 4;
    int2 lo = *(const int2*)&lrow[sr * 528 + kp * 64 + qk * 8];
    int2 hi = *(const int2*)&lrow[sr * 528 + kp * 64 + 32 + qk * 8];
    outp[idx] = make_int4(lo.x, lo.y, hi.x, hi.y);
  }
}

// K1 v15: v14's gram kernel (unchanged compute: 128x128 tiles, 4 waves,
// fine sub-phases, dbuf LDS DMA — 56.6us measured) FUSED with k_final via
// completion counters (zb words 60=gram_cnt target 2504, 61=bn_cnt target
// 14). Finisher blocks 2504..2608: fid<98 BN-out (waits bn_cnt only ->
// overlaps gram compute); fid 98..104 per-class KDE+affinity (waits all).
// Release: producers __syncthreads() (drains all waves' stores to L2) then
// t==0 __threadfence() (device-scope wb) + counter atomicAdd. Acquire:
// spin atomicAdd(cnt,0) + __threadfence(). Deadlock-free: 105 spinners <<
// 1024 block slots; producers never wait on finishers. Saves one launch +
// gap; BN-out fully hidden under gram.
__global__ __launch_bounds__(256, 4) void k_gram(const char* __restrict__ f8p,
                                                 const float* __restrict__ an,
                                                 const float* __restrict__ logits,
                                                 float* __restrict__ S,
                                                 float* __restrict__ rs_part,
                                                 float* __restrict__ S1,
                                                 float* __restrict__ S2,
                                                 const float* __restrict__ gamma,
                                                 const float* __restrict__ beta,
                                                 float* __restrict__ out) {
  int t = threadIdx.x, lane = t & 63, wave = t >> 6;
  unsigned* cntg = (unsigned*)(S1 + 60);   // zb word 60 (zeroed by k_prep)
  unsigned* cntb = (unsigned*)(S1 + 61);   // zb word 61

  __shared__ char ldsA[2][8192];
  __shared__ char ldsB[2][8192];
  __shared__ float bacc[4];

  if (blockIdx.x >= 2504) {  // ---- finisher blocks ----
    int fid = blockIdx.x - 2504;
    if (fid < 98) {
      // BN-out: needs only the 14 BN-stat blocks -> overlaps gram compute
      if (t == 0)
        while (atomicAdd(cntb, 0u) < 14u) __builtin_amdgcn_s_sleep(32);
      __syncthreads();
      __threadfence();
#pragma unroll
      for (int k = 0; k < 4; ++k) {
        int idx = fid * 1024 + k * 256 + t;  // 98*1024 = 100352 exactly
        int row = idx / 7;
        int c = idx - row * 7;
        float mu = S1[c] * (1.f / 14336.f);
        float var = S2[c] * (1.f / 14336.f) - mu * mu;
        out[idx] = gamma[c] * (logits[idx] - mu) * rsqrtf(var + 1e-5f) + beta[c];
      }
      return;
    }
    // KDE + affinity term: needs all gram blocks
    int c = fid - 98;
    if (t == 0)
      while (atomicAdd(cntg, 0u) < 2504u) __builtin_amdgcn_s_sleep(32);
    __syncthreads();
    __threadfence();
    const float LOG_NORM = 345.9110632f;  // -256*ln(2*pi*0.04) - ln(2048)
    float v = 0.f;
    for (int i = t; i < M_CLS; i += 256) {
      int bi = i >> 7;                    // 128-row block index (0..15)
      const float* rp = rs_part + (size_t)(c * M_CLS + i) * 64;
      float rsum = 0.f;
      const float2* rpd = (const float2*)rp;
      for (int k = 0; k <= bi; ++k) {     // direct: (bi+1) float2s
        float2 xx = rpd[k];
        rsum += xx.x + xx.y;
      }
      const float2* rpm = (const float2*)(rp + 34 + 2 * bi);
      for (int k = 0; k < 15 - bi; ++k) { // mirror: (15-bi) float2s
        float2 xx = rpm[k];
        rsum += xx.x + xx.y;
      }
      v += 1.f / (logf(rsum) + LOG_NORM);
    }
#pragma unroll
    for (int o = 1; o < 64; o <<= 1) v += __shfl_xor(v, o);
    if (lane == 0) bacc[wave] = v;
    __syncthreads();
    if (t == 0) {
      float vs = bacc[0] + bacc[1] + bacc[2] + bacc[3];
      float w = 1.f / (vs + 1e-5f);
      const float inv_m2 = 1.0f / ((float)M_CLS * (float)M_CLS);
      float Ssrc = S[c];
      float Stgt = (c > 0) ? S[0] : S[1];
      float X    = (c > 0) ? S[6 + c] : S[7];  // cross Sidx 7+p is (p+1,0)
      float mmd = (Ssrc + Stgt - 2.f * X) * inv_m2;
      atomicAdd(&out[100352], -mmd * w);
    }
    return;
  }

  int x = blockIdx.x & 7, u = blockIdx.x >> 3;
  if (blockIdx.x == 0 && t == 0) out[100352] = 0.f;

  if (u >= 311) {  // BN stats: 14 blocks x 4 wave-jobs = 56 = (class, seg)
    int blk;
    if (u == 311) blk = x;
    else {
      if (x >= 6) {  // 2 idle blocks still count toward gram_cnt
        if (t == 0) atomicAdd(cntg, 1u);
        return;
      }
      blk = 8 + x;
    }
    int idx = blk * 4 + wave;          // 0..55
    int c = idx >> 3, seg = idx & 7;
    int r0 = seg * 1792;
    float s1 = 0.f, s2 = 0.f;
    for (int j = lane; j < 1792; j += 64) {
      float v = logits[(size_t)(r0 + j) * 7 + c];
      s1 += v;
      s2 += v * v;
    }
#pragma unroll
    for (int o = 1; o < 64; o <<= 1) {
      s1 += __shfl_xor(s1, o);
      s2 += __shfl_xor(s2, o);
    }
    if (lane == 0) { atomicAdd(&S1[c], s1); atomicAdd(&S2[c], s2); }
    __syncthreads();
    if (t == 0) {
      __threadfence();
      atomicAdd(cntb, 1u);
      atomicAdd(cntg, 1u);
    }
    return;
  }

  int cls1, cls2, ti, tj, Sidx;
  bool self;
  if (x < 7 && u < 136) {
    int a = 0, r = u;
    while (r > a) { r -= a + 1; ++a; }  // u = a(a+1)/2 + r, r<=a (a<=15)
    ti = a; tj = r;                     // tj <= ti
    cls1 = x; cls2 = x; Sidx = x; self = true;
  } else {
    int j;
    if (x < 7) j = x * 175 + (u - 136);        // 0..1224
    else j = 1225 + u;                         // 1225..1535
    int p = j >> 8, t256 = j & 255;
    ti = t256 >> 4; tj = t256 & 15;
    cls1 = p + 1; cls2 = 0; Sidx = 7 + p; self = false;
  }

  int R0 = cls1 * 2048 + ti * 128;
  int C0 = cls2 * 2048 + tj * 128;

  // staging: wave stages row-group chunks {2w, 2w+1} of A and B per K-tile
  const char* gA0 = f8p + ((size_t)(R0 >> 4) + wave * 2)     * 8192 + lane * 16;
  const char* gA1 = f8p + ((size_t)(R0 >> 4) + wave * 2 + 1) * 8192 + lane * 16;
  const char* gB0 = f8p + ((size_t)(C0 >> 4) + wave * 2)     * 8192 + lane * 16;
  const char* gB1 = f8p + ((size_t)(C0 >> 4) + wave * 2 + 1) * 8192 + lane * 16;

  int wr = wave >> 1, wc = wave & 1;   // 2M x 2N wave grid, wave = 64x64
  int q = lane >> 4, s = lane & 15;

  f32x4 acc[4][4];
#pragma unroll
  for (int i = 0; i < 4; ++i)
#pragma unroll
    for (int j = 0; j < 4; ++j)
      acc[i][j] = (f32x4){0.f, 0.f, 0.f, 0.f};

  // prologue: stage tile 0 fully, drain, publish
  gload16(gA0, &ldsA[0][(wave * 2) * 1024 + lane * 16]);
  gload16(gA1, &ldsA[0][(wave * 2 + 1) * 1024 + lane * 16]);
  gload16(gB0, &ldsB[0][(wave * 2) * 1024 + lane * 16]);
  gload16(gB1, &ldsB[0][(wave * 2 + 1) * 1024 + lane * 16]);
  __syncthreads();

#define MM16(A0_, A1_, I0_, I1_)                                              \
  do {                                                                        \
    asm volatile("s_waitcnt lgkmcnt(0)" ::: "memory");                        \
    __builtin_amdgcn_sched_barrier(0);                                        \
    __builtin_amdgcn_s_setprio(1);                                            \
    _Pragma("unroll")                                                         \
    for (int j_ = 0; j_ < 4; ++j_)                                            \
      acc[I0_][j_] = __builtin_amdgcn_mfma_f32_16x16x32_fp8_fp8(              \
          A0_.x, bb[j_].x, acc[I0_][j_], 0, 0, 0);                            \
    _Pragma("unroll")                                                         \
    for (int j_ = 0; j_ < 4; ++j_)                                            \
      acc[I1_][j_] = __builtin_amdgcn_mfma_f32_16x16x32_fp8_fp8(              \
          A1_.x, bb[j_].x, acc[I1_][j_], 0, 0, 0);                            \
    _Pragma("unroll")                                                         \
    for (int j_ = 0; j_ < 4; ++j_)                                            \
      acc[I0_][j_] = __builtin_amdgcn_mfma_f32_16x16x32_fp8_fp8(              \
          A0_.y, bb[j_].y, acc[I0_][j_], 0, 0, 0);                            \
    _Pragma("unroll")                                                         \
    for (int j_ = 0; j_ < 4; ++j_)                                            \
      acc[I1_][j_] = __builtin_amdgcn_mfma_f32_16x16x32_fp8_fp8(              \
          A1_.y, bb[j_].y, acc[I1_][j_], 0, 0, 0);                            \
    __builtin_amdgcn_s_setprio(0);                                            \
  } while (0)

#pragma unroll 1
  for (int kt = 0; kt < 8; ++kt) {
    int cur = kt & 1;
    const char* LA = &ldsA[cur][(wr * 4) * 1024 + lane * 16];
    const char* LB = &ldsB[cur][(wc * 4) * 1024 + lane * 16];
    longlong2 a0, a1, bb[4];
    // ---- phase 0: i = 0,1 ----
    a0 = *(const longlong2*)(LA);
    a1 = *(const longlong2*)(LA + 1024);
#pragma unroll
    for (int j = 0; j < 4; ++j) bb[j] = *(const longlong2*)(LB + j * 1024);
    if (kt < 7) {  // stage next tile, part 1 (A chunks)
      int nb = cur ^ 1;
      gload16(gA0 + (kt + 1) * 1024, &ldsA[nb][(wave * 2) * 1024 + lane * 16]);
      gload16(gA1 + (kt + 1) * 1024, &ldsA[nb][(wave * 2 + 1) * 1024 + lane * 16]);
    }
    MM16(a0, a1, 0, 1);
    // ---- phase 1: i = 2,3 (ds issued under phase-0 MFMA shadow) ----
    a0 = *(const longlong2*)(LA + 2 * 1024);
    a1 = *(const longlong2*)(LA + 3 * 1024);
    if (kt < 7) {  // stage next tile, part 2 (B chunks)
      int nb = cur ^ 1;
      gload16(gB0 + (kt + 1) * 1024, &ldsB[nb][(wave * 2) * 1024 + lane * 16]);
      gload16(gB1 + (kt + 1) * 1024, &ldsB[nb][(wave * 2 + 1) * 1024 + lane * 16]);
    }
    __builtin_amdgcn_s_barrier();
    asm volatile("" ::: "memory");
    MM16(a0, a1, 2, 3);
    // ---- kt boundary: publish next buffer (4 loads, >=1 phase old) ----
    if (kt < 7)
      asm volatile("s_waitcnt vmcnt(0)" ::: "memory");
    __builtin_amdgcn_s_barrier();
    asm volatile("" ::: "memory");
  }
#undef MM16

  // Epilogue. C/D (16x16x32): col=lane&15, row=(lane>>4)*4+reg.
  bool dg = self && (ti == tj);
  bool mirror = self && (ti > tj);
  float blockAcc = 0.f;
  float colAcc[4] = {0.f, 0.f, 0.f, 0.f};
  float anB_[4];
#pragma unroll
  for (int j = 0; j < 4; ++j) anB_[j] = an[C0 + wc * 64 + j * 16 + s];

#pragma unroll
  for (int i = 0; i < 4; ++i) {
    f32x4 anA_ = *(const f32x4*)&an[R0 + wr * 64 + i * 16 + q * 4];
#pragma unroll
    for (int rg = 0; rg < 4; ++rg) {
      int rl = wr * 64 + i * 16 + q * 4 + rg;
      float aA = anA_[rg];
      float rowAcc = 0.f;
#pragma unroll
      for (int j = 0; j < 4; ++j) {
        int cl = wc * 64 + j * 16 + s;
        float g = acc[i][j][rg];
        float d2 = fmaxf(aA + anB_[j] - g * INV_2S2, 0.f);
        if (dg && rl == cl) d2 = 0.f;  // exact diagonal
        float e1 = __expf(-0.05f * d2);
        float e2 = e1 * e1, e4 = e2 * e2, e8 = e4 * e4, e16 = e8 * e8;
        blockAcc += e1 + e2 + e4 + e8 + e16;
        if (self) {
          float ek = __expf(-12.5f * d2);  // KDE: 1/(2*0.2^2)
          rowAcc += ek;
          if (mirror) colAcc[j] += ek;
        }
      }
      if (self) {
        rowAcc += __shfl_xor(rowAcc, 1);
        rowAcc += __shfl_xor(rowAcc, 2);
        rowAcc += __shfl_xor(rowAcc, 4);
        rowAcc += __shfl_xor(rowAcc, 8);
        if (s == 0)
          rs_part[(size_t)(R0 + rl) * 64 + tj * 2 + wc] = rowAcc;
      }
    }
  }
  if (mirror) {
#pragma unroll
    for (int j = 0; j < 4; ++j) {
      float v = colAcc[j];
      v += __shfl_xor(v, 16);
      v += __shfl_xor(v, 32);
      if (q == 0)
        rs_part[(size_t)(C0 + wc * 64 + j * 16 + s) * 64 + 32 + ti * 2 + wr] = v;
    }
    blockAcc *= 2.f;  // mirror tile counted once
  }
#pragma unroll
  for (int o = 1; o < 64; o <<= 1) blockAcc += __shfl_xor(blockAcc, o);
  if (lane == 0) bacc[wave] = blockAcc;
  __syncthreads();   // also drains all waves' rs_part stores (vmcnt 0)
  if (t == 0) {
    atomicAdd(&S[Sidx], bacc[0] + bacc[1] + bacc[2] + bacc[3]);
    __threadfence();               // device-scope writeback of block stores
    atomicAdd(cntg, 1u);
  }
}

extern "C" void kernel_launch(void* const* d_in, const int* in_sizes, int n_in,
                              void* d_out, int out_size, void* d_ws, size_t ws_size,
                              hipStream_t stream) {
  const float* fea   = (const float*)d_in[0];
  const float* W_fc  = (const float*)d_in[1];
  const float* gamma = (const float*)d_in[2];
  const float* beta  = (const float*)d_in[3];
  float* out = (float*)d_out;

  char* ws = (char*)d_ws;
  char* f8p = ws;                                // packed fp8 image: 7,340,032 B
  float* fbase   = (float*)(ws + 7340032);
  float* an      = fbase;                        // 14336
  float* logits  = fbase + 14336;                // 100352
  float* zb      = fbase + 114688;               // 64-float zero block
  float* S1      = zb;                           //   [0..6]; counters at [60],[61]
  float* S2      = zb + 7;                       //   [7..13]
  float* S       = zb + 16;                      //   [16..28] (13 used)
  float* rs_part = fbase + 114752;               // 14336*64 (valid slots only)

  k_prep <<<896,  256, 0, stream>>>(fea, W_fc, f8p, an, logits, zb);
  k_gram <<<2609, 256, 0, stream>>>(f8p, an, logits, S, rs_part, S1, S2,
                                    gamma, beta, out);
}

// Round 16
// 158.879 us; speedup vs baseline: 1.7260x; 1.7260x over previous
//
#include <hip/hip_runtime.h>

#define B_ROWS 14336
#define D_DIM  512
#define C_CLS  7
#define M_CLS  2048

typedef __attribute__((ext_vector_type(4))) float f32x4;

// fp8 scale: fea*64 -> sigma~3.2 in e4m3 range; Gram scaled by 4096
#define FP8_SCALE 64.0f
#define INV_2S2   (2.0f / 4096.0f)

typedef const __attribute__((address_space(1))) char gchar_t;
typedef __attribute__((address_space(3))) char lchar_t;

__device__ __forceinline__ void gload16(const char* g, char* l) {
  // async global->LDS DMA, 16B/lane, dest = wave-uniform base + lane*16
  __builtin_amdgcn_global_load_lds((gchar_t*)g, (lchar_t*)l, 16, 0, 0);
}

// K0: fea->fp8 packed in fragment-order image + row norms + logits + zero zb.
// Image layout: 16B at (r16, kp, l) = byte ((r16*8 + kp)*64 + l)*16, holding
// row r16*16 + (l&15), k-bytes {kp*64 + (l>>4)*8 ..+7} (.x) and {+32..} (.y).
__global__ __launch_bounds__(256) void k_prep(const float* __restrict__ fea,
                                              const float* __restrict__ W,
                                              char* __restrict__ f8p,
                                              float* __restrict__ an,
                                              float* __restrict__ logits,
                                              float* __restrict__ zb) {  // 64 floats
  int t = threadIdx.x, wave = t >> 6, lane = t & 63;
  if (blockIdx.x == 0 && t < 64) zb[t] = 0.f;
  __shared__ char lrow[16 * 528];  // 16 rows x 512B fp8 (+16 pad)

  int r0 = blockIdx.x * 16;
#pragma unroll
  for (int k = 0; k < 4; ++k) {
    int rl = wave * 4 + k;
    int row = r0 + rl;
    const float4* fr4 = (const float4*)(fea + (size_t)row * D_DIM);
    float4 v0 = fr4[lane * 2], v1 = fr4[lane * 2 + 1];

    float p[8];
#pragma unroll
    for (int c = 0; c < 7; ++c) {
      const float4* w4 = (const float4*)(W + c * D_DIM);
      float4 q0 = w4[lane * 2], q1 = w4[lane * 2 + 1];
      p[c] = v0.x * q0.x + v0.y * q0.y + v0.z * q0.z + v0.w * q0.w +
             v1.x * q1.x + v1.y * q1.y + v1.z * q1.z + v1.w * q1.w;
    }
    p[7] = v0.x * v0.x + v0.y * v0.y + v0.z * v0.z + v0.w * v0.w +
           v1.x * v1.x + v1.y * v1.y + v1.z * v1.z + v1.w * v1.w;

#pragma unroll
    for (int c = 0; c < 8; ++c) {
      p[c] += __shfl_xor(p[c], 1);
      p[c] += __shfl_xor(p[c], 2);
      p[c] += __shfl_xor(p[c], 4);
    }
    int v = lane & 7;
    float y = p[0];
    y = (v == 1) ? p[1] : y;
    y = (v == 2) ? p[2] : y;
    y = (v == 3) ? p[3] : y;
    y = (v == 4) ? p[4] : y;
    y = (v == 5) ? p[5] : y;
    y = (v == 6) ? p[6] : y;
    y = (v == 7) ? p[7] : y;
    y += __shfl_xor(y, 8);
    y += __shfl_xor(y, 16);
    y += __shfl_xor(y, 32);
    if (lane < 7) logits[row * 7 + lane] = y;
    else if (lane == 7) an[row] = y;

    int w0 = __builtin_amdgcn_cvt_pk_fp8_f32(v0.x * FP8_SCALE, v0.y * FP8_SCALE, 0, 0);
    w0     = __builtin_amdgcn_cvt_pk_fp8_f32(v0.z * FP8_SCALE, v0.w * FP8_SCALE, w0, 1);
    int w1 = __builtin_amdgcn_cvt_pk_fp8_f32(v1.x * FP8_SCALE, v1.y * FP8_SCALE, 0, 0);
    w1     = __builtin_amdgcn_cvt_pk_fp8_f32(v1.z * FP8_SCALE, v1.w * FP8_SCALE, w1, 1);
    *(int2*)&lrow[rl * 528 + lane * 8] = make_int2(w0, w1);
  }
  __syncthreads();
  int4* outp = (int4*)f8p + (size_t)blockIdx.x * 512;
#pragma unroll
  for (int pi = 0; pi < 2; ++pi) {
    int idx = pi * 256 + t;          // [0,512) = (kp, l)
    int kp = idx >> 6, l = idx & 63;
    int sr = l & 15, qk = l >> 4;
    int2 lo = *(const int2*)&lrow[sr * 528 + kp * 64 + qk * 8];
    int2 hi = *(const int2*)&lrow[sr * 528 + kp * 64 + 32 + qk * 8];
    outp[idx] = make_int4(lo.x, lo.y, hi.x, hi.y);
  }
}

// K1 v14 (REVERT from v15 fusion): 128x128 tiles, 4 waves (2Mx2N, wave =
// 64x64 = 4x4 frags), BK=64, dbuf A+B LDS via global_load_lds, fine
// sub-phases. Measured 56.6us, MfmaUtil 30%, total 156.6us (round 14 best).
// Round-15 postmortem: counter-fusion regressed 156->274us — per-producer
// __threadfence() = L2 writeback x2504 thrashed the L2-resident f8p image
// (MfmaUtil 30->8.4%, WRITE 2.2->7.8MB) + 105 spinners contending the zb
// atomic line. Fusion on non-coherent-L2 costs a per-producer L2 flush ->
// only viable with tiny producer counts. Reverted verbatim.
// Grid 2504 = 313 u x 8 xcd:
//   x<7 : u<136 self class x (tri 16x16); u in [136,311): cross
//         j = x*175 + (u-136)  (j<1225)
//   x==7: u<311 cross j = 1225+u
//   u==311 (all x): BN block idx=x; u==312 (x<6): BN block idx=8+x
// rs_part 64 slots/row: direct tj*2+wc in [0,2bi+2); mirror 32+ti*2+wr in
// [34+2bi,64). Exactly-once; k_final reads only valid ranges.
__global__ __launch_bounds__(256, 4) void k_gram(const char* __restrict__ f8p,
                                                 const float* __restrict__ an,
                                                 const float* __restrict__ logits,
                                                 float* __restrict__ S,
                                                 float* __restrict__ rs_part,
                                                 float* __restrict__ S1,
                                                 float* __restrict__ S2,
                                                 float* __restrict__ aff) {
  int x = blockIdx.x & 7, u = blockIdx.x >> 3;
  int t = threadIdx.x, lane = t & 63, wave = t >> 6;
  if (blockIdx.x == 0 && t == 0) aff[0] = 0.f;

  if (u >= 311) {  // BN stats: 14 blocks x 4 wave-jobs = 56 = (class, seg)
    int blk;
    if (u == 311) blk = x;
    else { if (x >= 6) return; blk = 8 + x; }
    int idx = blk * 4 + wave;          // 0..55
    int c = idx >> 3, seg = idx & 7;
    int r0 = seg * 1792;
    float s1 = 0.f, s2 = 0.f;
    for (int j = lane; j < 1792; j += 64) {
      float v = logits[(size_t)(r0 + j) * 7 + c];
      s1 += v;
      s2 += v * v;
    }
#pragma unroll
    for (int o = 1; o < 64; o <<= 1) {
      s1 += __shfl_xor(s1, o);
      s2 += __shfl_xor(s2, o);
    }
    if (lane == 0) { atomicAdd(&S1[c], s1); atomicAdd(&S2[c], s2); }
    return;
  }

  int cls1, cls2, ti, tj, Sidx;
  bool self;
  if (x < 7 && u < 136) {
    int a = 0, r = u;
    while (r > a) { r -= a + 1; ++a; }  // u = a(a+1)/2 + r, r<=a (a<=15)
    ti = a; tj = r;                     // tj <= ti
    cls1 = x; cls2 = x; Sidx = x; self = true;
  } else {
    int j;
    if (x < 7) j = x * 175 + (u - 136);        // 0..1224
    else j = 1225 + u;                         // 1225..1535
    int p = j >> 8, t256 = j & 255;
    ti = t256 >> 4; tj = t256 & 15;
    cls1 = p + 1; cls2 = 0; Sidx = 7 + p; self = false;
  }

  __shared__ char ldsA[2][8192];
  __shared__ char ldsB[2][8192];
  __shared__ float bacc[4];

  int R0 = cls1 * 2048 + ti * 128;
  int C0 = cls2 * 2048 + tj * 128;

  // staging: wave stages row-group chunks {2w, 2w+1} of A and B per K-tile
  const char* gA0 = f8p + ((size_t)(R0 >> 4) + wave * 2)     * 8192 + lane * 16;
  const char* gA1 = f8p + ((size_t)(R0 >> 4) + wave * 2 + 1) * 8192 + lane * 16;
  const char* gB0 = f8p + ((size_t)(C0 >> 4) + wave * 2)     * 8192 + lane * 16;
  const char* gB1 = f8p + ((size_t)(C0 >> 4) + wave * 2 + 1) * 8192 + lane * 16;

  int wr = wave >> 1, wc = wave & 1;   // 2M x 2N wave grid, wave = 64x64
  int q = lane >> 4, s = lane & 15;

  f32x4 acc[4][4];
#pragma unroll
  for (int i = 0; i < 4; ++i)
#pragma unroll
    for (int j = 0; j < 4; ++j)
      acc[i][j] = (f32x4){0.f, 0.f, 0.f, 0.f};

  // prologue: stage tile 0 fully, drain, publish
  gload16(gA0, &ldsA[0][(wave * 2) * 1024 + lane * 16]);
  gload16(gA1, &ldsA[0][(wave * 2 + 1) * 1024 + lane * 16]);
  gload16(gB0, &ldsB[0][(wave * 2) * 1024 + lane * 16]);
  gload16(gB1, &ldsB[0][(wave * 2 + 1) * 1024 + lane * 16]);
  __syncthreads();

#define MM16(A0_, A1_, I0_, I1_)                                              \
  do {                                                                        \
    asm volatile("s_waitcnt lgkmcnt(0)" ::: "memory");                        \
    __builtin_amdgcn_sched_barrier(0);                                        \
    __builtin_amdgcn_s_setprio(1);                                            \
    _Pragma("unroll")                                                         \
    for (int j_ = 0; j_ < 4; ++j_)                                            \
      acc[I0_][j_] = __builtin_amdgcn_mfma_f32_16x16x32_fp8_fp8(              \
          A0_.x, bb[j_].x, acc[I0_][j_], 0, 0, 0);                            \
    _Pragma("unroll")                                                         \
    for (int j_ = 0; j_ < 4; ++j_)                                            \
      acc[I1_][j_] = __builtin_amdgcn_mfma_f32_16x16x32_fp8_fp8(              \
          A1_.x, bb[j_].x, acc[I1_][j_], 0, 0, 0);                            \
    _Pragma("unroll")                                                         \
    for (int j_ = 0; j_ < 4; ++j_)                                            \
      acc[I0_][j_] = __builtin_amdgcn_mfma_f32_16x16x32_fp8_fp8(              \
          A0_.y, bb[j_].y, acc[I0_][j_], 0, 0, 0);                            \
    _Pragma("unroll")                                                         \
    for (int j_ = 0; j_ < 4; ++j_)                                            \
      acc[I1_][j_] = __builtin_amdgcn_mfma_f32_16x16x32_fp8_fp8(              \
          A1_.y, bb[j_].y, acc[I1_][j_], 0, 0, 0);                            \
    __builtin_amdgcn_s_setprio(0);                                            \
  } while (0)

#pragma unroll 1
  for (int kt = 0; kt < 8; ++kt) {
    int cur = kt & 1;
    const char* LA = &ldsA[cur][(wr * 4) * 1024 + lane * 16];
    const char* LB = &ldsB[cur][(wc * 4) * 1024 + lane * 16];
    longlong2 a0, a1, bb[4];
    // ---- phase 0: i = 0,1 ----
    a0 = *(const longlong2*)(LA);
    a1 = *(const longlong2*)(LA + 1024);
#pragma unroll
    for (int j = 0; j < 4; ++j) bb[j] = *(const longlong2*)(LB + j * 1024);
    if (kt < 7) {  // stage next tile, part 1 (A chunks)
      int nb = cur ^ 1;
      gload16(gA0 + (kt + 1) * 1024, &ldsA[nb][(wave * 2) * 1024 + lane * 16]);
      gload16(gA1 + (kt + 1) * 1024, &ldsA[nb][(wave * 2 + 1) * 1024 + lane * 16]);
    }
    MM16(a0, a1, 0, 1);
    // ---- phase 1: i = 2,3 (ds issued under phase-0 MFMA shadow) ----
    a0 = *(const longlong2*)(LA + 2 * 1024);
    a1 = *(const longlong2*)(LA + 3 * 1024);
    if (kt < 7) {  // stage next tile, part 2 (B chunks)
      int nb = cur ^ 1;
      gload16(gB0 + (kt + 1) * 1024, &ldsB[nb][(wave * 2) * 1024 + lane * 16]);
      gload16(gB1 + (kt + 1) * 1024, &ldsB[nb][(wave * 2 + 1) * 1024 + lane * 16]);
    }
    __builtin_amdgcn_s_barrier();
    asm volatile("" ::: "memory");
    MM16(a0, a1, 2, 3);
    // ---- kt boundary: publish next buffer (4 loads, >=1 phase old) ----
    if (kt < 7)
      asm volatile("s_waitcnt vmcnt(0)" ::: "memory");
    __builtin_amdgcn_s_barrier();
    asm volatile("" ::: "memory");
  }
#undef MM16

  // Epilogue. C/D (16x16x32): col=lane&15, row=(lane>>4)*4+reg.
  bool dg = self && (ti == tj);
  bool mirror = self && (ti > tj);
  float blockAcc = 0.f;
  float colAcc[4] = {0.f, 0.f, 0.f, 0.f};
  float anB_[4];
#pragma unroll
  for (int j = 0; j < 4; ++j) anB_[j] = an[C0 + wc * 64 + j * 16 + s];

#pragma unroll
  for (int i = 0; i < 4; ++i) {
    f32x4 anA_ = *(const f32x4*)&an[R0 + wr * 64 + i * 16 + q * 4];
#pragma unroll
    for (int rg = 0; rg < 4; ++rg) {
      int rl = wr * 64 + i * 16 + q * 4 + rg;
      float aA = anA_[rg];
      float rowAcc = 0.f;
#pragma unroll
      for (int j = 0; j < 4; ++j) {
        int cl = wc * 64 + j * 16 + s;
        float g = acc[i][j][rg];
        float d2 = fmaxf(aA + anB_[j] - g * INV_2S2, 0.f);
        if (dg && rl == cl) d2 = 0.f;  // exact diagonal
        float e1 = __expf(-0.05f * d2);
        float e2 = e1 * e1, e4 = e2 * e2, e8 = e4 * e4, e16 = e8 * e8;
        blockAcc += e1 + e2 + e4 + e8 + e16;
        if (self) {
          float ek = __expf(-12.5f * d2);  // KDE: 1/(2*0.2^2)
          rowAcc += ek;
          if (mirror) colAcc[j] += ek;
        }
      }
      if (self) {
        rowAcc += __shfl_xor(rowAcc, 1);
        rowAcc += __shfl_xor(rowAcc, 2);
        rowAcc += __shfl_xor(rowAcc, 4);
        rowAcc += __shfl_xor(rowAcc, 8);
        if (s == 0)
          rs_part[(size_t)(R0 + rl) * 64 + tj * 2 + wc] = rowAcc;
      }
    }
  }
  if (mirror) {
#pragma unroll
    for (int j = 0; j < 4; ++j) {
      float v = colAcc[j];
      v += __shfl_xor(v, 16);
      v += __shfl_xor(v, 32);
      if (q == 0)
        rs_part[(size_t)(C0 + wc * 64 + j * 16 + s) * 64 + 32 + ti * 2 + wr] = v;
    }
    blockAcc *= 2.f;  // mirror tile counted once
  }
#pragma unroll
  for (int o = 1; o < 64; o <<= 1) blockAcc += __shfl_xor(blockAcc, o);
  if (lane == 0) bacc[wave] = blockAcc;
  __syncthreads();
  if (t == 0)
    atomicAdd(&S[Sidx], bacc[0] + bacc[1] + bacc[2] + bacc[3]);
}

// K2: bnout (blocks 0..97, 1024 thr) + per-class KDE weight & affinity
// (blocks 98..104). rs_part 64 slots/row; valid per block-row bi (128-row
// blocks): direct [0,2bi+2) = (bi+1) float2s; mirror [34+2bi,64) = (15-bi)
// float2s (8B-aligned: even offsets, 256B row stride).
__global__ __launch_bounds__(1024) void k_final(const float* __restrict__ logits,
                                                const float* __restrict__ S1,
                                                const float* __restrict__ S2,
                                                const float* __restrict__ gamma,
                                                const float* __restrict__ beta,
                                                const float* __restrict__ rs_part,
                                                const float* __restrict__ S,
                                                float* __restrict__ out) {
  int b = blockIdx.x, t = threadIdx.x;
  if (b < 98) {
    int idx = b * 1024 + t;  // 98*1024 = 100352 exactly
    int row = idx / 7;
    int c = idx - row * 7;
    float mu = S1[c] * (1.f / 14336.f);
    float var = S2[c] * (1.f / 14336.f) - mu * mu;
    out[idx] = gamma[c] * (logits[idx] - mu) * rsqrtf(var + 1e-5f) + beta[c];
    return;
  }
  int c = b - 98;
  // log_norm = -256*ln(2*pi*0.04) - ln(2048)
  const float LOG_NORM = 345.9110632f;
  float v = 0.f;
  for (int i = t; i < M_CLS; i += 1024) {
    int bi = i >> 7;                          // 128-row block index (0..15)
    const float* rp = rs_part + (size_t)(c * M_CLS + i) * 64;
    float rsum = 0.f;
    const float2* rpd = (const float2*)rp;
    for (int k = 0; k <= bi; ++k) {           // direct: (bi+1) float2s
      float2 xx = rpd[k];
      rsum += xx.x + xx.y;
    }
    const float2* rpm = (const float2*)(rp + 34 + 2 * bi);
    for (int k = 0; k < 15 - bi; ++k) {       // mirror: (15-bi) float2s
      float2 xx = rpm[k];
      rsum += xx.x + xx.y;
    }
    v += 1.f / (logf(rsum) + LOG_NORM);
  }
#pragma unroll
  for (int o = 1; o < 64; o <<= 1) v += __shfl_xor(v, o);
  __shared__ float r[16];
  if ((t & 63) == 0) r[t >> 6] = v;
  __syncthreads();
  if (t == 0) {
    float vs = 0.f;
#pragma unroll
    for (int w = 0; w < 16; ++w) vs += r[w];
    float w = 1.f / (vs + 1e-5f);
    const float inv_m2 = 1.0f / ((float)M_CLS * (float)M_CLS);
    float Ssrc = S[c];
    float Stgt = (c > 0) ? S[0] : S[1];
    float X    = (c > 0) ? S[6 + c] : S[7];  // cross Sidx 7+p is (p+1,0)
    float mmd = (Ssrc + Stgt - 2.f * X) * inv_m2;
    atomicAdd(&out[100352], -mmd * w);
  }
}

extern "C" void kernel_launch(void* const* d_in, const int* in_sizes, int n_in,
                              void* d_out, int out_size, void* d_ws, size_t ws_size,
                              hipStream_t stream) {
  const float* fea   = (const float*)d_in[0];
  const float* W_fc  = (const float*)d_in[1];
  const float* gamma = (const float*)d_in[2];
  const float* beta  = (const float*)d_in[3];
  float* out = (float*)d_out;

  char* ws = (char*)d_ws;
  char* f8p = ws;                                // packed fp8 image: 7,340,032 B
  float* fbase   = (float*)(ws + 7340032);
  float* an      = fbase;                        // 14336
  float* logits  = fbase + 14336;                // 100352
  float* zb      = fbase + 114688;               // 64-float zero block
  float* S1      = zb;                           //   [0..6]
  float* S2      = zb + 7;                       //   [7..13]
  float* S       = zb + 16;                      //   [16..28] (13 used)
  float* rs_part = fbase + 114752;               // 14336*64 (valid slots only)

  k_prep <<<896,  256, 0, stream>>>(fea, W_fc, f8p, an, logits, zb);
  k_gram <<<2504, 256, 0, stream>>>(f8p, an, logits, S, rs_part, S1, S2,
                                    out + 100352);
  k_final<<<105, 1024, 0, stream>>>(logits, S1, S2, gamma, beta, rs_part, S, out);
}